// Round 16
// baseline (656.415 us; speedup 1.0000x reference)
//
#include <hip/hip_runtime.h>

// W8A8 static-quant linear, M=8192 K=4096 N=11008. out = fp32((xq@W^T + qb)*dq)
// Decode (validated R14/R15, absmax 0.5): x fp32[M,K]-C, W i32-widened i8
// [N,K]-C, dq f32[N], isc f32[1], qb i32[N], iof i32[1], out fp32[M,N]-C.
// R16 = T4 counted-vmcnt depth-2 pipeline (catalog: counted IS the 8-phase
// gain, m218). 3 LDS buffers; stage(t) issued at t-2 -> ~2 compute phases of
// latency hiding; barriers NEVER drain vmcnt to 0 in the main loop.

#define MDIM 8192
#define KDIM 4096
#define NDIM 11008

#define BM 128
#define BN 128
#define BK 64
#define TM (MDIM / BM)   // 64
#define TN (NDIM / BN)   // 86
#define NWG (TM * TN)    // 5504
#define CPX (NWG / 8)    // 688
#define KSTEPS (KDIM / BK)  // 64

using int32x4  = __attribute__((ext_vector_type(4))) int;
using int32x16 = __attribute__((ext_vector_type(16))) int;
using floatx4  = __attribute__((ext_vector_type(4))) float;
using uint32x2 = __attribute__((ext_vector_type(2))) unsigned int;

__device__ __forceinline__ void gload_lds16(const void* g, void* l) {
    __builtin_amdgcn_global_load_lds(
        (__attribute__((address_space(1))) unsigned int*)g,
        (__attribute__((address_space(3))) unsigned int*)l,
        16, 0, 0);
}

__device__ __forceinline__ int quant1(float f, float inv, float off) {
    float r = rintf(f * inv) + off;          // jnp: round half-even, then clip
    r = fminf(127.f, fmaxf(-128.f, r));
    return (int)r;
}

__device__ __forceinline__ int pack4i(int a, int b, int c, int d) {
    return (a & 255) | ((b & 255) << 8) | ((c & 255) << 16) | ((d & 255) << 24);
}

struct Resolved { const float* dq; const int* qb; float inv; float off; };
__device__ __forceinline__ Resolved resolve4(const void* p11a, const void* p11b) {
    Resolved r;
    int a_is_dq = 1;
#pragma unroll
    for (int j = 0; j < 8; ++j) {
        const float v = ((const float*)p11a)[j];
        a_is_dq &= (v > 1e-6f) & (v < 1e-2f);   // deq ~1e-4; int bits: denorm/neg
    }
    r.dq = a_is_dq ? (const float*)p11a : (const float*)p11b;
    r.qb = a_is_dq ? (const int*)p11b : (const int*)p11a;
    r.inv = 0.f; r.off = 0.f;
    return r;
}

__device__ __forceinline__ void resolve_scale(const void* p1a, const void* p1b,
                                              float* inv, float* off) {
    const float fa = ((const float*)p1a)[0];
    const int a_is_isc = (fa > 1e-3f) & (fa < 1.0f);  // isc in [0.02,0.045]
    const float iscv = a_is_isc ? ((const float*)p1a)[0] : ((const float*)p1b)[0];
    *inv = 1.0f / iscv;
    *off = (float)(a_is_isc ? ((const int*)p1b)[0] : ((const int*)p1a)[0]);
}

// ---------------- pass 1a: x fp32 -> int8 ----------------
__global__ __launch_bounds__(256)
void quant_x(const float* __restrict__ X, const void* p1a, const void* p1b,
             signed char* __restrict__ xq) {
    float inv, off;
    resolve_scale(p1a, p1b, &inv, &off);
    const long long nch = (long long)MDIM * KDIM / 8;
    const long long stride = (long long)gridDim.x * 256;
    for (long long i = (long long)blockIdx.x * 256 + threadIdx.x; i < nch; i += stride) {
        floatx4 v0 = ((const floatx4*)X)[2 * i];
        floatx4 v1 = ((const floatx4*)X)[2 * i + 1];
        int q[8];
#pragma unroll
        for (int j = 0; j < 4; ++j) {
            q[j]     = quant1(v0[j], inv, off);
            q[4 + j] = quant1(v1[j], inv, off);
        }
        uint32x2 o;
        o[0] = (unsigned)pack4i(q[0], q[1], q[2], q[3]);
        o[1] = (unsigned)pack4i(q[4], q[5], q[6], q[7]);
        ((uint32x2*)xq)[i] = o;
    }
}

// ---------------- pass 1b: weight int32 -> int8 ----------------
__global__ __launch_bounds__(256)
void pack_w(const int* __restrict__ Wi, signed char* __restrict__ W8) {
    const long long nch = (long long)NDIM * KDIM / 8;
    const long long stride = (long long)gridDim.x * 256;
    for (long long i = (long long)blockIdx.x * 256 + threadIdx.x; i < nch; i += stride) {
        int32x4 a = ((const int32x4*)Wi)[2 * i];
        int32x4 b = ((const int32x4*)Wi)[2 * i + 1];
        uint32x2 o;
        o[0] = (unsigned)pack4i(a[0], a[1], a[2], a[3]);
        o[1] = (unsigned)pack4i(b[0], b[1], b[2], b[3]);
        ((uint32x2*)W8)[i] = o;
    }
}

// -- pass 2: int8 MFMA GEMM, depth-2 counted-vmcnt pipeline, fp32 epilogue --
// LDS per buffer: row r (0..127) x 4 phys 16B chunks; logical chunk c at
// phys p = c ^ ((r>>1)&3); inverse swizzle on the global source (rule #21).
// Pipeline: stage(t) issued at t-2. Each stage = 4 vmem instrs/wave
// (2 A + 2 B). Main-loop wait = vmcnt(8) (the 2 newer stages stay in
// flight); tail 4 -> 0. Raw s_barrier (no drain) + sched_barrier fence.
__global__ __launch_bounds__(256, 3)
void gemm_i8(const signed char* __restrict__ Aq, const signed char* __restrict__ W8,
             const void* p11a, const void* p11b,
             float* __restrict__ out) {
    __shared__ alignas(16) signed char As[3][BM * BK];   // 3 x 8KB
    __shared__ alignas(16) signed char Bs[3][BN * BK];   // 3 x 8KB

    const int tid  = threadIdx.x;
    const int lane = tid & 63;
    const int wv   = tid >> 6;
    const int l5   = lane >> 5;
    const int lr   = lane & 31;
    const int wm   = wv >> 1;      // 2x2 wave grid, each wave owns 64x64
    const int wn   = wv & 1;

    const int bid = blockIdx.x;
    const int wg  = (bid & 7) * CPX + (bid >> 3);   // bijective XCD swizzle
    const int m0  = (wg & (TM - 1)) * BM;
    const int n0  = (wg >> 6) * BN;

    int32x16 acc[2][2];
#pragma unroll
    for (int i = 0; i < 2; ++i)
#pragma unroll
        for (int j = 0; j < 2; ++j)
#pragma unroll
            for (int e = 0; e < 16; ++e) acc[i][j][e] = 0;

    // issue stage of K-step kt into buffer buf: exactly 4 vmem instrs/wave
    auto stage = [&](int buf, int kt) {
        const int kb = kt * BK;
#pragma unroll
        for (int j = 0; j < 2; ++j) {
            const int ci = (wv << 6) + (j << 8) + lane;
            const int r  = ci >> 2;
            const int p  = ci & 3;
            const int c  = p ^ ((r >> 1) & 3);      // inverse swizzle on source
            signed char* dstA = &As[buf][((wv << 6) + (j << 8)) << 4];
            signed char* dstB = &Bs[buf][((wv << 6) + (j << 8)) << 4];
            gload_lds16(Aq + (size_t)(m0 + r) * KDIM + kb + (c << 4), dstA);
            gload_lds16(W8 + (size_t)(n0 + r) * KDIM + kb + (c << 4), dstB);
        }
    };

    stage(0, 0);
    stage(1, 1);

    int cur = 0, nb2 = 2;
    for (int kt = 0; kt < KSTEPS; ++kt) {
        if (kt + 2 < KSTEPS) {
            stage(nb2, kt + 2);
            // stage(kt) landed; stage(kt+1), stage(kt+2) stay in flight
            asm volatile("s_waitcnt vmcnt(8)" ::: "memory");
        } else if (kt + 1 < KSTEPS) {
            asm volatile("s_waitcnt vmcnt(4)" ::: "memory");
        } else {
            asm volatile("s_waitcnt vmcnt(0)" ::: "memory");
        }
        __builtin_amdgcn_s_barrier();          // all waves: buf[cur] ready
        __builtin_amdgcn_sched_barrier(0);     // fence: no ds_read hoisting

        const signed char* Ab = As[cur];
        const signed char* Bb = Bs[cur];
        __builtin_amdgcn_s_setprio(1);
#pragma unroll
        for (int ks = 0; ks < 2; ++ks) {
            int32x4 af[2], bf[2];
#pragma unroll
            for (int mt = 0; mt < 2; ++mt) {
                const int r = wm * 64 + mt * 32 + lr;
                const int p = (ks * 2 + l5) ^ ((r >> 1) & 3);
                af[mt] = *(const int32x4*)(Ab + (r << 6) + (p << 4));
            }
#pragma unroll
            for (int nt = 0; nt < 2; ++nt) {
                const int r = wn * 64 + nt * 32 + lr;
                const int p = (ks * 2 + l5) ^ ((r >> 1) & 3);
                bf[nt] = *(const int32x4*)(Bb + (r << 6) + (p << 4));
            }
#pragma unroll
            for (int mt = 0; mt < 2; ++mt)
#pragma unroll
                for (int nt = 0; nt < 2; ++nt)
                    acc[mt][nt] = __builtin_amdgcn_mfma_i32_32x32x32_i8(
                        af[mt], bf[nt], acc[mt][nt], 0, 0, 0);
        }
        __builtin_amdgcn_s_setprio(0);
        // reads of buf[cur] complete here (ds_reads consumed by MFMAs above);
        // next iter re-stages into buf[cur] only after this barrier.
        __builtin_amdgcn_s_barrier();

        cur = (cur == 2) ? 0 : cur + 1;
        nb2 = (nb2 == 2) ? 0 : nb2 + 1;
    }

    // epilogue: (acc + qb[n]) * dq[n] -> fp32, C-order [M,N]
    // C/D layout (HW-verified): col = lane&31, row = (reg&3)+8*(reg>>2)+4*(lane>>5)
    const Resolved rs = resolve4(p11a, p11b);
#pragma unroll
    for (int nt = 0; nt < 2; ++nt) {
        const int gn   = n0 + wn * 64 + nt * 32 + lr;
        const int qbn  = rs.qb[gn];
        const float dq = rs.dq[gn];
#pragma unroll
        for (int mt = 0; mt < 2; ++mt) {
            const int gmb = m0 + wm * 64 + mt * 32 + (l5 << 2);
#pragma unroll
            for (int v = 0; v < 16; ++v) {
                const int gm = gmb + (v & 3) + ((v >> 2) << 3);
                out[(size_t)gm * NDIM + gn] = (float)(acc[mt][nt][v] + qbn) * dq;
            }
        }
    }
}

__global__ void codek(float* __restrict__ out) {
    out[blockIdx.x * 64 + threadIdx.x] = 51200.f;
}

extern "C" void kernel_launch(void* const* d_in, const int* in_sizes, int n_in,
                              void* d_out, int out_size, void* d_ws, size_t ws_size,
                              hipStream_t stream) {
    float* out = (float*)d_out;

    // order-robust pointer resolution by size fingerprint
    int ix = -1, iw = -1, i11[2] = {-1, -1}, i1[2] = {-1, -1};
    int n11 = 0, n1 = 0;
    bool bad = (n_in != 6);
    for (int i = 0; i < n_in && !bad; ++i) {
        const int s = in_sizes[i];
        if (s == MDIM * KDIM && ix < 0) ix = i;
        else if (s == NDIM * KDIM && iw < 0) iw = i;
        else if (s == NDIM && n11 < 2) i11[n11++] = i;
        else if (s == 1 && n1 < 2) i1[n1++] = i;
        else bad = true;
    }
    const size_t xq_bytes = (size_t)MDIM * KDIM;  // 33.5 MB
    const size_t w8_bytes = (size_t)NDIM * KDIM;  // 45.1 MB
    if (bad || ix < 0 || iw < 0 || n11 != 2 || n1 != 2 ||
        ws_size < xq_bytes + w8_bytes) {
        codek<<<dim3(100), dim3(64), 0, stream>>>(out);
        return;
    }

    const float* X  = (const float*)d_in[ix];
    const int*   Wi = (const int*)d_in[iw];
    const void*  pa = d_in[i11[0]];
    const void*  pb = d_in[i11[1]];
    const void*  pc = d_in[i1[0]];
    const void*  pd = d_in[i1[1]];

    signed char* xq = (signed char*)d_ws;
    signed char* w8 = xq + xq_bytes;

    quant_x<<<dim3(2048), dim3(256), 0, stream>>>(X, pc, pd, xq);
    pack_w<<<dim3(2048), dim3(256), 0, stream>>>(Wi, w8);
    gemm_i8<<<dim3(NWG), dim3(256), 0, stream>>>(xq, w8, pa, pb, out);
}